// Round 10
// baseline (166.311 us; speedup 1.0000x reference)
//
#include <hip/hip_runtime.h>

#define NN 5000
#define NE 40000

typedef unsigned int u32;
typedef unsigned short u16;
typedef __fp16 h16x2 __attribute__((ext_vector_type(2)));
typedef _Float16 f16x8 __attribute__((ext_vector_type(8)));
typedef __attribute__((ext_vector_type(4))) float f32x4;

union AF { u32 u[4]; f16x8 v; uint4 q; };

__device__ __forceinline__ float siluf(float x) { return x / (1.f + __expf(-x)); }

__device__ __forceinline__ u32 f2bf_u(float f) {
  u32 x = __float_as_uint(f);
  return (x + 0x7FFFu + ((x >> 16) & 1u)) >> 16;  // RNE
}
__device__ __forceinline__ u16 f2bf(float f) { return (u16)f2bf_u(f); }
__device__ __forceinline__ u32 packbf2(float lo, float hi) {
  return f2bf_u(lo) | (f2bf_u(hi) << 16);
}
__device__ __forceinline__ u32 pkh2(float a, float b) {
  union { h16x2 h; u32 u; } r;
  r.h = __builtin_amdgcn_cvt_pkrtz(a, b);
  return r.u;
}
__device__ __forceinline__ u16 f2h(float v) {
  _Float16 h = (_Float16)v;
  return *(u16*)&h;
}
__device__ __forceinline__ void unpack8(uint4 q, float* f) {
  f[0] = __uint_as_float(q.x << 16); f[1] = __uint_as_float(q.x & 0xFFFF0000u);
  f[2] = __uint_as_float(q.y << 16); f[3] = __uint_as_float(q.y & 0xFFFF0000u);
  f[4] = __uint_as_float(q.z << 16); f[5] = __uint_as_float(q.z & 0xFFFF0000u);
  f[6] = __uint_as_float(q.w << 16); f[7] = __uint_as_float(q.w & 0xFFFF0000u);
}
__device__ __forceinline__ float dot8f(const float* h, const float* w, float init) {
  float a = init;
#pragma unroll
  for (int k = 0; k < 8; k++) a = fmaf(h[k], w[k], a);
  return a;
}
__device__ __forceinline__ void mlp8(const float* ea, const float* __restrict__ W0,
                                     const float* __restrict__ b0, float* h) {
#pragma unroll
  for (int j = 0; j < 8; j++) {
    float a = b0[j];
#pragma unroll
    for (int i = 0; i < 8; i++) a += ea[i] * W0[i*8 + j];
    h[j] = siluf(a);
  }
}
__device__ __forceinline__ AF mkfrag(float hs, const float* s) {
  AF a;
  a.u[0] = pkh2(hs*s[0], hs*s[1]);
  a.u[1] = pkh2(hs*s[2], hs*s[3]);
  a.u[2] = pkh2(hs*s[4], hs*s[5]);
  a.u[3] = pkh2(hs*s[6], hs*s[7]);
  return a;
}

// ---- k_prep: pre-transpose ipW1 ONLY (8 blocks) — conv1's sole dependency.
__global__ __launch_bounds__(256) void k_prep(
    const float* __restrict__ ipW1, const float* __restrict__ ipb1,
    u16* __restrict__ ipT) {
  int t0 = blockIdx.x*2304 + threadIdx.x*9;
#pragma unroll
  for (int j = 0; j < 9; j++) {
    int t = t0 + j;               // 0..18431
    int kch = t >> 9, rem = t & 511;
    int col = rem >> 3, kk = rem & 7;
    int k = kch*8 + kk;
    int pth = col >> 5, w = col & 31;
    float v = (k < 256) ? ipW1[(k >> 5)*2048 + pth*1024 + (k & 31)*32 + w]
                        : ipb1[pth*1024 + (k - 256)*32 + w];
    ipT[t] = f2h(v);
  }
}

// ---- conv1: TWO waves per 16-edge tile (half 0: scalar streams + side effects;
// half 1: vector streams). ZERO LDS/barriers; B-fragments from ipT (L2).
// Blocks >= 1250 pre-transpose lyW1 -> lyT for conv2 (overlapped).
__global__ __launch_bounds__(256) void k_conv1(
    const float* __restrict__ coords, const int* __restrict__ eidx,
    const float* __restrict__ emb, const int* __restrict__ atype,
    const float* __restrict__ ipW0, const float* __restrict__ ipb0,
    const float* __restrict__ lyW0, const float* __restrict__ lyb0,
    const float* __restrict__ etW0, const float* __restrict__ etb0,
    const float* __restrict__ lyW1, const float* __restrict__ lyb1,
    const u16* __restrict__ ipT,
    float* __restrict__ sh, float* __restrict__ h_ly, float* __restrict__ h_et,
    int* __restrict__ cur, int* __restrict__ perm,
    u16* __restrict__ msg, u16* __restrict__ lyT) {
  if (blockIdx.x >= 1250) {
    int b = blockIdx.x - 1250;      // 0..15
    int h = b >> 3;
    int t0 = (b & 7)*2304 + threadIdx.x*9;
#pragma unroll
    for (int j = 0; j < 9; j++) {
      int t = t0 + j;               // 0..18431
      int kch = t >> 9, rem = t & 511;
      int col = rem >> 3, kk = rem & 7;
      int k = kch*8 + kk;
      int basec = (h == 0) ? ((col >> 5)*1024 + (col & 31))
                           : ((col < 32) ? (2048 + col) : (3072 + (col - 32)));
      float v = (k < 256) ? lyW1[(k >> 5)*4096 + basec + (k & 31)*32]
                          : lyb1[basec + (k - 256)*32];
      lyT[h*18432 + t] = f2h(v);
    }
    return;
  }
  int wid = threadIdx.x >> 6, lane = threadIdx.x & 63;
  int gw = blockIdx.x*4 + wid;              // 0..4999 (2 waves/tile)
  int tile = gw >> 1, half = gw & 1;
  int m = lane & 15, q = lane >> 4;
  int e = tile*16 + m;
  int s = eidx[e], d = eidx[NE + e];
  // hoisted atomics (half 0 only): start the device-scope round-trip ASAP
  if (half == 0 && q == 0) {
    int* cp = &cur[d];
    atomicCAS(cp, (int)0xAAAAAAAA, 0);   // first-touch zero (poison sentinel)
    int t = atomicAdd(cp, 1);
    if (t < 64) perm[d*64 + t] = e;
  }
  int srow = atype[s];
  float vx = coords[d*3+0] - coords[s*3+0];
  float vy = coords[d*3+1] - coords[s*3+1];
  float vz = coords[d*3+2] - coords[s*3+2];
  float dist = sqrtf(vx*vx + vy*vy + vz*vz + 1e-12f);
  float dinv = 1.f / dist;
  const float SQ3 = 1.7320508075688772f;
  float sh0 = SQ3 * vy * dinv;   // e3nn (y,z,x)
  float sh1 = SQ3 * vz * dinv;
  float sh2 = SQ3 * vx * dinv;
  float ea[8];
  const float step = 5.f / 9.f;
#pragma unroll
  for (int jj = 0; jj < 8; jj++) {
    float diff = (dist - step * (float)(jj+1)) * (9.f / 5.f);
    ea[jj] = __expf(-diff*diff) * (1.f / 1.12f);
  }
  float hip[8];
  mlp8(ea, ipW0, ipb0, hip);
  if (half == 0) {          // wave-uniform branch: only half 0 needs hly/het
    float hly[8], het[8];
    mlp8(ea, lyW0, lyb0, hly);
    mlp8(ea, etW0, etb0, het);
    if (q == 0) {
      sh[e*3+0] = sh0; sh[e*3+1] = sh1; sh[e*3+2] = sh2;
      { float4 f0 = {hly[0],hly[1],hly[2],hly[3]}, f1 = {hly[4],hly[5],hly[6],hly[7]};
        *(float4*)&h_ly[e*8] = f0; *(float4*)&h_ly[e*8+4] = f1; }
      { float4 f0 = {het[0],het[1],het[2],het[3]}, f1 = {het[4],het[5],het[6],het[7]};
        *(float4*)&h_et[e*8] = f0; *(float4*)&h_et[e*8+4] = f1; }
    }
  }
  float4 sA = *(const float4*)&emb[srow*32 + q*8];
  float4 sB = *(const float4*)&emb[srow*32 + q*8 + 4];
  float sf[8] = {sA.x,sA.y,sA.z,sA.w,sB.x,sB.y,sB.z,sB.w};
  const float cs = 0.17677669529663687f;   // 1/sqrt(32)
  if (half == 0) {
    f32x4 acc0 = {0.f,0.f,0.f,0.f}, acc1 = acc0;
#pragma unroll
    for (int ks = 0; ks < 9; ks++) {
      float hs = (ks < 8) ? hip[ks] : 1.f;
      AF a = mkfrag(hs, sf);
      int c2 = (ks*4 + q)*64;
      AF b0, b1f;
      b0.q  = *(const uint4*)&ipT[(c2 +  0 + m)*8];
      b1f.q = *(const uint4*)&ipT[(c2 + 16 + m)*8];
      acc0 = __builtin_amdgcn_mfma_f32_16x16x32_f16(a.v, b0.v,  acc0, 0, 0, 0);
      acc1 = __builtin_amdgcn_mfma_f32_16x16x32_f16(a.v, b1f.v, acc1, 0, 0, 0);
    }
#pragma unroll
    for (int r = 0; r < 4; r++) {
      int et = tile*16 + q*4 + r;
      u16* mp = msg + (size_t)et*128;
      mp[m]      = f2bf(cs*acc0[r]);
      mp[16 + m] = f2bf(cs*acc1[r]);
    }
  } else {
    f32x4 acc2 = {0.f,0.f,0.f,0.f}, acc3 = acc2;
#pragma unroll
    for (int ks = 0; ks < 9; ks++) {
      float hs = (ks < 8) ? hip[ks] : 1.f;
      AF a = mkfrag(hs, sf);
      int c2 = (ks*4 + q)*64;
      AF b2, b3;
      b2.q = *(const uint4*)&ipT[(c2 + 32 + m)*8];
      b3.q = *(const uint4*)&ipT[(c2 + 48 + m)*8];
      acc2 = __builtin_amdgcn_mfma_f32_16x16x32_f16(a.v, b2.v, acc2, 0, 0, 0);
      acc3 = __builtin_amdgcn_mfma_f32_16x16x32_f16(a.v, b3.v, acc3, 0, 0, 0);
    }
#pragma unroll
    for (int r = 0; r < 4; r++) {
      int et = tile*16 + q*4 + r;
      u16* mp = msg + (size_t)et*128;
      float s0v = __shfl(sh0, q*4 + r, 64);
      float s1v = __shfl(sh1, q*4 + r, 64);
      float s2v = __shfl(sh2, q*4 + r, 64);
      float m0 = cs*acc2[r], m1 = cs*acc3[r];
      mp[32 +      m] = f2bf(m0*s0v);
      mp[64 +      m] = f2bf(m0*s1v);
      mp[96 +      m] = f2bf(m0*s2v);
      mp[32 + 16 + m] = f2bf(m1*s0v);
      mp[64 + 16 + m] = f2bf(m1*s1v);
      mp[96 + 16 + m] = f2bf(m1*s2v);
    }
  }
}

// ---- conv2: TWO waves per tile for both halves (grid 2500 blocks = 10000 waves);
// ZERO LDS/barriers; B-fragments from lyT (L2) ----
__global__ __launch_bounds__(256) void k_conv2(
    const float* __restrict__ hE, const float* __restrict__ sh,
    const float* __restrict__ s1, const float* __restrict__ v1soa,
    const int* __restrict__ eidx, const u16* __restrict__ lyT,
    u16* __restrict__ msgA, u16* __restrict__ msgB) {
  int wid = threadIdx.x >> 6, lane = threadIdx.x & 63;
  int gw = blockIdx.x*4 + wid;             // 0..9999
  const bool scalarKind = gw < 5000;
  int t2 = scalarKind ? gw : gw - 5000;
  int tile = t2 >> 1, half = t2 & 1;
  int m = lane & 15, q = lane >> 4;
  const u16* Bg = lyT + (scalarKind ? 0 : 18432);
  const float c = 0.125f;  // 1/sqrt(64)
  int e = tile*16 + m;
  int srcn = eidx[e];
  float4 hA = *(const float4*)&hE[e*8];
  float4 hB = *(const float4*)&hE[e*8 + 4];
  float hf[8] = {hA.x,hA.y,hA.z,hA.w,hB.x,hB.y,hB.z,hB.w};

  if (scalarKind) {
    float4 sA = *(const float4*)&s1[srcn*32 + q*8];
    float4 sB = *(const float4*)&s1[srcn*32 + q*8 + 4];
    float sf[8] = {sA.x,sA.y,sA.z,sA.w,sB.x,sB.y,sB.z,sB.w};
    if (half == 0) {
      f32x4 acc0 = {0.f,0.f,0.f,0.f}, acc1 = acc0;
#pragma unroll
      for (int ks = 0; ks < 9; ks++) {
        float hs = (ks < 8) ? hf[ks] : 1.f;
        AF a = mkfrag(hs, sf);
        int c2 = (ks*4 + q)*64;
        AF b0, b1f;
        b0.q  = *(const uint4*)&Bg[(c2 +  0 + m)*8];
        b1f.q = *(const uint4*)&Bg[(c2 + 16 + m)*8];
        acc0 = __builtin_amdgcn_mfma_f32_16x16x32_f16(a.v, b0.v,  acc0, 0, 0, 0);
        acc1 = __builtin_amdgcn_mfma_f32_16x16x32_f16(a.v, b1f.v, acc1, 0, 0, 0);
      }
#pragma unroll
      for (int r = 0; r < 4; r++) {
        int et = tile*16 + q*4 + r;
        u16* mp = msgA + (size_t)et*128;
        mp[m]      = f2bf(c*acc0[r]);
        mp[16 + m] = f2bf(c*acc1[r]);
      }
    } else {
      f32x4 acc2 = {0.f,0.f,0.f,0.f}, acc3 = acc2;
#pragma unroll
      for (int ks = 0; ks < 9; ks++) {
        float hs = (ks < 8) ? hf[ks] : 1.f;
        AF a = mkfrag(hs, sf);
        int c2 = (ks*4 + q)*64;
        AF b2, b3;
        b2.q = *(const uint4*)&Bg[(c2 + 32 + m)*8];
        b3.q = *(const uint4*)&Bg[(c2 + 48 + m)*8];
        acc2 = __builtin_amdgcn_mfma_f32_16x16x32_f16(a.v, b2.v, acc2, 0, 0, 0);
        acc3 = __builtin_amdgcn_mfma_f32_16x16x32_f16(a.v, b3.v, acc3, 0, 0, 0);
      }
#pragma unroll
      for (int r = 0; r < 4; r++) {
        int et = tile*16 + q*4 + r;
        u16* mp = msgA + (size_t)et*128;
        float s0v = sh[et*3+0], s1v = sh[et*3+1], s2v = sh[et*3+2];
        float m0 = c*acc2[r], m1 = c*acc3[r];
        mp[32 +      m] = f2bf(m0*s0v);
        mp[64 +      m] = f2bf(m0*s1v);
        mp[96 +      m] = f2bf(m0*s2v);
        mp[32 + 16 + m] = f2bf(m1*s0v);
        mp[64 + 16 + m] = f2bf(m1*s1v);
        mp[96 + 16 + m] = f2bf(m1*s2v);
      }
    }
  } else {
    const float is3 = 0.5773502691896258f;
    if (half == 0) {
      // aV00,aV01 (a0) and aV10,aV11 (a1): needs vf0, vf1 only
      float vf0[8], vf1[8];
#pragma unroll
      for (int i = 0; i < 2; i++) {
        float* dst = (i == 0) ? vf0 : vf1;
        float4 aa = *(const float4*)&v1soa[i*160000 + srcn*32 + q*8];
        float4 bb = *(const float4*)&v1soa[i*160000 + srcn*32 + q*8 + 4];
        dst[0]=aa.x; dst[1]=aa.y; dst[2]=aa.z; dst[3]=aa.w;
        dst[4]=bb.x; dst[5]=bb.y; dst[6]=bb.z; dst[7]=bb.w;
      }
      f32x4 z = {0.f,0.f,0.f,0.f};
      f32x4 aV00 = z, aV01 = z, aV10 = z, aV11 = z;
#pragma unroll
      for (int ks = 0; ks < 9; ks++) {
        float hs = (ks < 8) ? hf[ks] : 1.f;
        int c2 = (ks*4 + q)*64;
        AF b0, b1f;
        b0.q  = *(const uint4*)&Bg[(c2 +  0 + m)*8];
        b1f.q = *(const uint4*)&Bg[(c2 + 16 + m)*8];
        AF a0 = mkfrag(hs, vf0);
        AF a1 = mkfrag(hs, vf1);
        aV00 = __builtin_amdgcn_mfma_f32_16x16x32_f16(a0.v, b0.v,  aV00, 0, 0, 0);
        aV01 = __builtin_amdgcn_mfma_f32_16x16x32_f16(a0.v, b1f.v, aV01, 0, 0, 0);
        aV10 = __builtin_amdgcn_mfma_f32_16x16x32_f16(a1.v, b0.v,  aV10, 0, 0, 0);
        aV11 = __builtin_amdgcn_mfma_f32_16x16x32_f16(a1.v, b1f.v, aV11, 0, 0, 0);
      }
#pragma unroll
      for (int r = 0; r < 4; r++) {
        int et = tile*16 + q*4 + r;
        u16* mp = msgB + (size_t)et*128;
        mp[32 +      m] = f2bf(c*aV00[r]);
        mp[32 + 16 + m] = f2bf(c*aV01[r]);
        mp[64 +      m] = f2bf(c*aV10[r]);
        mp[64 + 16 + m] = f2bf(c*aV11[r]);
      }
    } else {
      // aV20,aV21 (a2) and aD0,aD1 (ad): needs vf0..2 (df) + sh
      float vf[3][8];
#pragma unroll
      for (int i = 0; i < 3; i++) {
        float4 aa = *(const float4*)&v1soa[i*160000 + srcn*32 + q*8];
        float4 bb = *(const float4*)&v1soa[i*160000 + srcn*32 + q*8 + 4];
        vf[i][0]=aa.x; vf[i][1]=aa.y; vf[i][2]=aa.z; vf[i][3]=aa.w;
        vf[i][4]=bb.x; vf[i][5]=bb.y; vf[i][6]=bb.z; vf[i][7]=bb.w;
      }
      float es0 = sh[e*3+0], es1 = sh[e*3+1], es2 = sh[e*3+2];
      float df[8];
#pragma unroll
      for (int j = 0; j < 8; j++)
        df[j] = (vf[0][j]*es0 + vf[1][j]*es1 + vf[2][j]*es2) * is3;
      f32x4 z = {0.f,0.f,0.f,0.f};
      f32x4 aV20 = z, aV21 = z, aD0 = z, aD1 = z;
#pragma unroll
      for (int ks = 0; ks < 9; ks++) {
        float hs = (ks < 8) ? hf[ks] : 1.f;
        int c2 = (ks*4 + q)*64;
        AF b0, b1f, b2, b3;
        b0.q  = *(const uint4*)&Bg[(c2 +  0 + m)*8];
        b1f.q = *(const uint4*)&Bg[(c2 + 16 + m)*8];
        b2.q  = *(const uint4*)&Bg[(c2 + 32 + m)*8];
        b3.q  = *(const uint4*)&Bg[(c2 + 48 + m)*8];
        AF a2 = mkfrag(hs, vf[2]);
        AF ad = mkfrag(hs, df);
        aV20 = __builtin_amdgcn_mfma_f32_16x16x32_f16(a2.v, b0.v,  aV20, 0, 0, 0);
        aV21 = __builtin_amdgcn_mfma_f32_16x16x32_f16(a2.v, b1f.v, aV21, 0, 0, 0);
        aD0  = __builtin_amdgcn_mfma_f32_16x16x32_f16(ad.v, b2.v,  aD0,  0, 0, 0);
        aD1  = __builtin_amdgcn_mfma_f32_16x16x32_f16(ad.v, b3.v,  aD1,  0, 0, 0);
      }
#pragma unroll
      for (int r = 0; r < 4; r++) {
        int et = tile*16 + q*4 + r;
        u16* mp = msgB + (size_t)et*128;
        mp[m]       = f2bf(c*aD0[r]);
        mp[16 + m]  = f2bf(c*aD1[r]);
        mp[96 +      m] = f2bf(c*aV20[r]);
        mp[96 + 16 + m] = f2bf(c*aV21[r]);
      }
    }
  }
}

// ---- gather + mean (conv1); perm in LDS; 4-way unrolled loads ----
__global__ __launch_bounds__(256) void k_gather1(
    const u16* __restrict__ msg, const int* __restrict__ perm,
    const int* __restrict__ cur, float* __restrict__ s1,
    float* __restrict__ v1soa) {
  __shared__ int pe[2][64];
  int ln = threadIdx.x >> 7, c = threadIdx.x & 127;
  int n = blockIdx.x*2 + ln;
  int deg = min(cur[n], 64);
  if (c < 64) pe[ln][c] = perm[n*64 + c];
  __syncthreads();
  float acc = 0.f;
  int j = 0;
  for (; j + 4 <= deg; j += 4) {
    int e0 = pe[ln][j], e1 = pe[ln][j+1], e2 = pe[ln][j+2], e3 = pe[ln][j+3];
    float x0 = __uint_as_float(((u32)msg[(size_t)e0*128 + c]) << 16);
    float x1 = __uint_as_float(((u32)msg[(size_t)e1*128 + c]) << 16);
    float x2 = __uint_as_float(((u32)msg[(size_t)e2*128 + c]) << 16);
    float x3 = __uint_as_float(((u32)msg[(size_t)e3*128 + c]) << 16);
    acc += (x0 + x1) + (x2 + x3);
  }
  for (; j < deg; j++)
    acc += __uint_as_float(((u32)msg[(size_t)pe[ln][j]*128 + c]) << 16);
  acc /= (float)max(deg, 1);
  if (c < 32) s1[n*32 + c] = acc;
  else { int i = (c-32) >> 5, w = (c-32) & 31; v1soa[i*160000 + n*32 + w] = acc; }
}

// ---- gather + mean (conv2) + self-interaction + node MLP; unrolled loads ----
__global__ __launch_bounds__(256) void k_gather2(
    const u16* __restrict__ msgA, const u16* __restrict__ msgB,
    const int* __restrict__ perm, const int* __restrict__ cur,
    const float* __restrict__ s1, const float* __restrict__ v1soa,
    const float* __restrict__ Ws, const float* __restrict__ Wv,
    const float* __restrict__ noW1, const float* __restrict__ noW2,
    float* __restrict__ s2, float* __restrict__ v2, float* __restrict__ outN) {
  __shared__ int pe[2][64];
  __shared__ float sb[2][32];
  __shared__ float hb[2][13];
  int ln = threadIdx.x >> 7, c = threadIdx.x & 127;
  int n = blockIdx.x*2 + ln;
  int deg = min(cur[n], 64);
  if (c < 64) pe[ln][c] = perm[n*64 + c];
  __syncthreads();
  float acc = 0.f;
  int j = 0;
  for (; j + 4 <= deg; j += 4) {
    int e0 = pe[ln][j], e1 = pe[ln][j+1], e2 = pe[ln][j+2], e3 = pe[ln][j+3];
    float x0 = __uint_as_float(((u32)msgA[(size_t)e0*128 + c]) << 16)
             + __uint_as_float(((u32)msgB[(size_t)e0*128 + c]) << 16);
    float x1 = __uint_as_float(((u32)msgA[(size_t)e1*128 + c]) << 16)
             + __uint_as_float(((u32)msgB[(size_t)e1*128 + c]) << 16);
    float x2 = __uint_as_float(((u32)msgA[(size_t)e2*128 + c]) << 16)
             + __uint_as_float(((u32)msgB[(size_t)e2*128 + c]) << 16);
    float x3 = __uint_as_float(((u32)msgA[(size_t)e3*128 + c]) << 16)
             + __uint_as_float(((u32)msgB[(size_t)e3*128 + c]) << 16);
    acc += (x0 + x1) + (x2 + x3);
  }
  for (; j < deg; j++) {
    int e = pe[ln][j];
    acc += __uint_as_float(((u32)msgA[(size_t)e*128 + c]) << 16)
         + __uint_as_float(((u32)msgB[(size_t)e*128 + c]) << 16);
  }
  acc /= (float)max(deg, 1);
  const float lc = 0.17677669529663687f;  // 1/sqrt(32)
  if (c < 32) {
    float ss = 0.f;
#pragma unroll 8
    for (int u = 0; u < 32; u++) ss += s1[n*32 + u] * Ws[u*32 + c];
    float val = acc + lc*ss;
    s2[n*32 + c] = val;
    sb[ln][c] = val;
  } else {
    int i = (c-32) >> 5, w = (c-32) & 31;
    float sv = 0.f;
#pragma unroll 8
    for (int u = 0; u < 32; u++) sv += v1soa[i*160000 + n*32 + u] * Wv[u*32 + w];
    v2[n*96 + w*3 + i] = acc + lc*sv;
  }
  __syncthreads();
  const float i32 = 0.17677669529663687f;
  if (c < 13) {
    float a = 0.f;
#pragma unroll 8
    for (int u = 0; u < 32; u++) a += sb[ln][u] * noW1[u*13 + c];
    hb[ln][c] = siluf(a * i32);
  }
  __syncthreads();
  const float i13 = 0.2773500981126146f;  // 1/sqrt(13)
  if (c < 13) {
    float a = 0.f;
#pragma unroll
    for (int j2 = 0; j2 < 13; j2++) a += hb[ln][j2] * noW2[j2*13 + c];
    outN[n*13 + c] = a * i13;
  }
}

// ---- edge output TP -> 5x0e; lanes = u, 2 edges per pass, path-major inner loop ----
__global__ __launch_bounds__(256) void k_e3(
    const float* __restrict__ hE, const float* __restrict__ sh,
    const float* __restrict__ s2, const float* __restrict__ v2,
    const int* __restrict__ eidx,
    const float* __restrict__ W1, const float* __restrict__ b1,
    float* __restrict__ out) {
  __shared__ uint4 WQ[640];   // [(p*5+w)*32 + u] : 8 bf16 k-values
  __shared__ float BQ[640];
  for (int t = threadIdx.x; t < 640; t += 256) {
    int u = t & 31, pw = t >> 5, p2 = pw / 5, w = pw - p2*5;
    int col = p2*160 + u*5 + w;
    const float* s = W1 + col;
    uint4 q;
    q.x = packbf2(s[0],      s[640]);
    q.y = packbf2(s[1280],   s[1920]);
    q.z = packbf2(s[2560],   s[3200]);
    q.w = packbf2(s[3840],   s[4480]);
    WQ[t] = q;
    BQ[t] = b1[col];
  }
  __syncthreads();
  const int g = threadIdx.x >> 5, tw = threadIdx.x & 31;
  const float c = 0.08838834764831845f;   // 1/sqrt(128)
  const float is3 = 0.5773502691896258f;
  for (int p = blockIdx.x*8 + g; p*2 < NE; p += gridDim.x*8) {
    int e0 = p*2, e1 = e0 + 1;
    float h0[8], h1[8];
    {
      float4 qa = *(const float4*)&hE[e0*8];
      float4 qb = *(const float4*)&hE[e0*8+4];
      h0[0]=qa.x; h0[1]=qa.y; h0[2]=qa.z; h0[3]=qa.w;
      h0[4]=qb.x; h0[5]=qb.y; h0[6]=qb.z; h0[7]=qb.w;
      float4 qc = *(const float4*)&hE[e1*8];
      float4 qd = *(const float4*)&hE[e1*8+4];
      h1[0]=qc.x; h1[1]=qc.y; h1[2]=qc.z; h1[3]=qc.w;
      h1[4]=qd.x; h1[5]=qd.y; h1[6]=qd.z; h1[7]=qd.w;
    }
    int sA = eidx[e0], dA = eidx[NE+e0];
    int sB = eidx[e1], dB = eidx[NE+e1];
    float sa0 = sh[e0*3+0], sa1 = sh[e0*3+1], sa2 = sh[e0*3+2];
    float sb0 = sh[e1*3+0], sb1 = sh[e1*3+1], sb2 = sh[e1*3+2];
    float c00 = s2[sA*32 + tw];
    float c01 = (v2[sA*96+tw*3+0]*sa0 + v2[sA*96+tw*3+1]*sa1 + v2[sA*96+tw*3+2]*sa2) * is3;
    float c02 = s2[dA*32 + tw];
    float c03 = (v2[dA*96+tw*3+0]*sa0 + v2[dA*96+tw*3+1]*sa1 + v2[dA*96+tw*3+2]*sa2) * is3;
    float c10 = s2[sB*32 + tw];
    float c11 = (v2[sB*96+tw*3+0]*sb0 + v2[sB*96+tw*3+1]*sb1 + v2[sB*96+tw*3+2]*sb2) * is3;
    float c12 = s2[dB*32 + tw];
    float c13 = (v2[dB*96+tw*3+0]*sb0 + v2[dB*96+tw*3+1]*sb1 + v2[dB*96+tw*3+2]*sb2) * is3;
    float part0[5] = {0,0,0,0,0};
    float part1[5] = {0,0,0,0,0};
#pragma unroll
    for (int pp = 0; pp < 4; pp++) {
      float cp0 = (pp==0) ? c00 : (pp==1) ? c01 : (pp==2) ? c02 : c03;
      float cp1 = (pp==0) ? c10 : (pp==1) ? c11 : (pp==2) ? c12 : c13;
#pragma unroll
      for (int w = 0; w < 5; w++) {
        int idx = (pp*5 + w)*32 + tw;
        float f[8];
        unpack8(WQ[idx], f);
        float bv = BQ[idx];
        part0[w] = fmaf(cp0, dot8f(h0, f, bv), part0[w]);
        part1[w] = fmaf(cp1, dot8f(h1, f, bv), part1[w]);
      }
    }
#pragma unroll
    for (int off = 16; off > 0; off >>= 1)
#pragma unroll
      for (int w = 0; w < 5; w++) {
        part0[w] += __shfl_xor(part0[w], off, 32);
        part1[w] += __shfl_xor(part1[w], off, 32);
      }
    float outv = 0.f;
#pragma unroll
    for (int w = 0; w < 5; w++) {
      if (tw == w)     outv = part0[w];
      if (tw == 5 + w) outv = part1[w];
    }
    if (tw < 10) out[e0*5 + tw] = c * outv;
  }
}

extern "C" void kernel_launch(void* const* d_in, const int* in_sizes, int n_in,
                              void* d_out, int out_size, void* d_ws, size_t ws_size,
                              hipStream_t stream) {
  (void)in_sizes; (void)n_in; (void)out_size; (void)ws_size;
  const float* coords = (const float*)d_in[0];
  const int*   atype  = (const int*)d_in[1];
  const int*   eidx   = (const int*)d_in[2];
  const float* emb    = (const float*)d_in[3];
  const float* ipW0 = (const float*)d_in[4];
  const float* ipb0 = (const float*)d_in[5];
  const float* ipW1 = (const float*)d_in[6];
  const float* ipb1 = (const float*)d_in[7];
  const float* lyW0 = (const float*)d_in[8];
  const float* lyb0 = (const float*)d_in[9];
  const float* lyW1 = (const float*)d_in[10];
  const float* lyb1 = (const float*)d_in[11];
  const float* lyWs = (const float*)d_in[12];
  const float* lyWv = (const float*)d_in[13];
  const float* etW0 = (const float*)d_in[14];
  const float* etb0 = (const float*)d_in[15];
  const float* etW1 = (const float*)d_in[16];
  const float* etb1 = (const float*)d_in[17];
  const float* noW1 = (const float*)d_in[18];
  const float* noW2 = (const float*)d_in[19];

  float* ws = (float*)d_ws;
  float* sh    = ws;                  // E*3
  float* h_ly  = ws + 440000;         // E*8
  float* h_et  = ws + 760000;         // E*8
  float* s1    = ws + 1240000;        // N*32
  float* v1soa = ws + 1400000;        // 3 x 160000 (SoA)
  float* s2    = ws + 1880000;        // N*32
  float* v2    = ws + 2040000;        // N*96 (AoS) -> ends 2520000
  int*   cur   = (int*)(ws + 2520000);   // N ints (poison sentinel, CAS-zeroed)
  int*   perm  = (int*)(ws + 2525000);   // N*64 ints
  u16*   msgA  = (u16*)(ws + 2845000);   // E*128 bf16
  u16*   msgB  = (u16*)(ws + 5405000);   // E*128 bf16 -> ends 7965000
  u16*   lyT   = (u16*)(ws + 7965000);   // 2*18432 f16 -> ends 7983432
  u16*   ipT   = (u16*)(ws + 7983432);   // 18432 f16

  float* outE = (float*)d_out;            // E*5
  float* outN = (float*)d_out + NE*5;     // N*13

  k_prep<<<8, 256, 0, stream>>>(ipW1, ipb1, ipT);
  k_conv1<<<1266, 256, 0, stream>>>(coords, eidx, emb, atype,
                                    ipW0, ipb0, lyW0, lyb0, etW0, etb0,
                                    lyW1, lyb1, ipT,
                                    sh, h_ly, h_et, cur, perm, msgA, lyT);
  k_gather1<<<NN/2, 256, 0, stream>>>(msgA, perm, cur, s1, v1soa);
  k_conv2<<<2500, 256, 0, stream>>>(h_ly, sh, s1, v1soa, eidx, lyT, msgA, msgB);
  k_gather2<<<NN/2, 256, 0, stream>>>(msgA, msgB, perm, cur, s1, v1soa,
                                      lyWs, lyWv, noW1, noW2, s2, v2, outN);
  k_e3<<<1024, 256, 0, stream>>>(h_et, sh, s2, v2, eidx, etW1, etb1, outE);
}

// Round 12
// 164.372 us; speedup vs baseline: 1.0118x; 1.0118x over previous
//
#include <hip/hip_runtime.h>

#define NN 5000
#define NE 40000

typedef unsigned int u32;
typedef unsigned short u16;
typedef __fp16 h16x2 __attribute__((ext_vector_type(2)));
typedef _Float16 f16x8 __attribute__((ext_vector_type(8)));
typedef __attribute__((ext_vector_type(4))) float f32x4;

union AF { u32 u[4]; f16x8 v; uint4 q; };

__device__ __forceinline__ float siluf(float x) { return x / (1.f + __expf(-x)); }

__device__ __forceinline__ u32 f2bf_u(float f) {
  u32 x = __float_as_uint(f);
  return (x + 0x7FFFu + ((x >> 16) & 1u)) >> 16;  // RNE
}
__device__ __forceinline__ u16 f2bf(float f) { return (u16)f2bf_u(f); }
__device__ __forceinline__ u32 packbf2(float lo, float hi) {
  return f2bf_u(lo) | (f2bf_u(hi) << 16);
}
__device__ __forceinline__ u32 pkh2(float a, float b) {
  union { h16x2 h; u32 u; } r;
  r.h = __builtin_amdgcn_cvt_pkrtz(a, b);
  return r.u;
}
__device__ __forceinline__ u16 f2h(float v) {
  _Float16 h = (_Float16)v;
  return *(u16*)&h;
}
__device__ __forceinline__ void unpack8(uint4 q, float* f) {
  f[0] = __uint_as_float(q.x << 16); f[1] = __uint_as_float(q.x & 0xFFFF0000u);
  f[2] = __uint_as_float(q.y << 16); f[3] = __uint_as_float(q.y & 0xFFFF0000u);
  f[4] = __uint_as_float(q.z << 16); f[5] = __uint_as_float(q.z & 0xFFFF0000u);
  f[6] = __uint_as_float(q.w << 16); f[7] = __uint_as_float(q.w & 0xFFFF0000u);
}
__device__ __forceinline__ float dot8f(const float* h, const float* w, float init) {
  float a = init;
#pragma unroll
  for (int k = 0; k < 8; k++) a = fmaf(h[k], w[k], a);
  return a;
}
__device__ __forceinline__ void mlp8(const float* ea, const float* __restrict__ W0,
                                     const float* __restrict__ b0, float* h) {
#pragma unroll
  for (int j = 0; j < 8; j++) {
    float a = b0[j];
#pragma unroll
    for (int i = 0; i < 8; i++) a += ea[i] * W0[i*8 + j];
    h[j] = siluf(a);
  }
}
__device__ __forceinline__ AF mkfrag(float hs, const float* s) {
  AF a;
  a.u[0] = pkh2(hs*s[0], hs*s[1]);
  a.u[1] = pkh2(hs*s[2], hs*s[3]);
  a.u[2] = pkh2(hs*s[4], hs*s[5]);
  a.u[3] = pkh2(hs*s[6], hs*s[7]);
  return a;
}

// ---- k_prep: pre-transpose ipW1 ONLY (8 blocks) — conv1's sole dependency.
// lyT (conv2's image) is produced by conv1's 16 extra blocks, overlapped.
__global__ __launch_bounds__(256) void k_prep(
    const float* __restrict__ ipW1, const float* __restrict__ ipb1,
    u16* __restrict__ ipT) {
  int t0 = blockIdx.x*2304 + threadIdx.x*9;
#pragma unroll
  for (int j = 0; j < 9; j++) {
    int t = t0 + j;               // 0..18431
    int kch = t >> 9, rem = t & 511;
    int col = rem >> 3, kk = rem & 7;
    int k = kch*8 + kk;
    int pth = col >> 5, w = col & 31;
    float v = (k < 256) ? ipW1[(k >> 5)*2048 + pth*1024 + (k & 31)*32 + w]
                        : ipb1[pth*1024 + (k - 256)*32 + w];
    ipT[t] = f2h(v);
  }
}

// ---- conv1: one wave per 16-edge tile, ZERO LDS, ZERO barriers.
// B-fragments from ipT (L2). Blocks >= 625 pre-transpose lyW1 -> lyT for conv2.
// Atomics hoisted before the radial MLPs to overlap their latency with VALU.
__global__ __launch_bounds__(256) void k_conv1(
    const float* __restrict__ coords, const int* __restrict__ eidx,
    const float* __restrict__ emb, const int* __restrict__ atype,
    const float* __restrict__ ipW0, const float* __restrict__ ipb0,
    const float* __restrict__ lyW0, const float* __restrict__ lyb0,
    const float* __restrict__ etW0, const float* __restrict__ etb0,
    const float* __restrict__ lyW1, const float* __restrict__ lyb1,
    const u16* __restrict__ ipT,
    float* __restrict__ sh, float* __restrict__ h_ly, float* __restrict__ h_et,
    int* __restrict__ cur, int* __restrict__ perm,
    u16* __restrict__ msg, u16* __restrict__ lyT) {
  if (blockIdx.x >= 625) {
    int b = blockIdx.x - 625;       // 0..15
    int h = b >> 3;
    int t0 = (b & 7)*2304 + threadIdx.x*9;
#pragma unroll
    for (int j = 0; j < 9; j++) {
      int t = t0 + j;               // 0..18431
      int kch = t >> 9, rem = t & 511;
      int col = rem >> 3, kk = rem & 7;
      int k = kch*8 + kk;
      int basec = (h == 0) ? ((col >> 5)*1024 + (col & 31))
                           : ((col < 32) ? (2048 + col) : (3072 + (col - 32)));
      float v = (k < 256) ? lyW1[(k >> 5)*4096 + basec + (k & 31)*32]
                          : lyb1[basec + (k - 256)*32];
      lyT[h*18432 + t] = f2h(v);
    }
    return;
  }
  int wid = threadIdx.x >> 6, lane = threadIdx.x & 63;
  int tile = blockIdx.x*4 + wid;            // 625 blocks -> 2500 tiles
  int m = lane & 15, q = lane >> 4;
  int e = tile*16 + m;
  int s = eidx[e], d = eidx[NE + e];
  // hoisted atomics: start the device-scope round-trip ASAP
  int t = 0;
  if (q == 0) {
    int* cp = &cur[d];
    atomicCAS(cp, (int)0xAAAAAAAA, 0);   // first-touch zero (poison sentinel)
    t = atomicAdd(cp, 1);
    if (t < 64) perm[d*64 + t] = e;
  }
  int srow = atype[s];
  float vx = coords[d*3+0] - coords[s*3+0];
  float vy = coords[d*3+1] - coords[s*3+1];
  float vz = coords[d*3+2] - coords[s*3+2];
  float dist = sqrtf(vx*vx + vy*vy + vz*vz + 1e-12f);
  float dinv = 1.f / dist;
  const float SQ3 = 1.7320508075688772f;
  float sh0 = SQ3 * vy * dinv;   // e3nn (y,z,x)
  float sh1 = SQ3 * vz * dinv;
  float sh2 = SQ3 * vx * dinv;
  float ea[8];
  const float step = 5.f / 9.f;
#pragma unroll
  for (int jj = 0; jj < 8; jj++) {
    float diff = (dist - step * (float)(jj+1)) * (9.f / 5.f);
    ea[jj] = __expf(-diff*diff) * (1.f / 1.12f);
  }
  float hip[8], hly[8], het[8];
  mlp8(ea, ipW0, ipb0, hip);
  mlp8(ea, lyW0, lyb0, hly);
  mlp8(ea, etW0, etb0, het);
  if (q == 0) {
    sh[e*3+0] = sh0; sh[e*3+1] = sh1; sh[e*3+2] = sh2;
    { float4 f0 = {hly[0],hly[1],hly[2],hly[3]}, f1 = {hly[4],hly[5],hly[6],hly[7]};
      *(float4*)&h_ly[e*8] = f0; *(float4*)&h_ly[e*8+4] = f1; }
    { float4 f0 = {het[0],het[1],het[2],het[3]}, f1 = {het[4],het[5],het[6],het[7]};
      *(float4*)&h_et[e*8] = f0; *(float4*)&h_et[e*8+4] = f1; }
  }
  // A-fragment source data (per-lane, no shuffles needed)
  float4 sA = *(const float4*)&emb[srow*32 + q*8];
  float4 sB = *(const float4*)&emb[srow*32 + q*8 + 4];
  float sf[8] = {sA.x,sA.y,sA.z,sA.w,sB.x,sB.y,sB.z,sB.w};
  f32x4 acc0 = {0.f,0.f,0.f,0.f}, acc1 = acc0, acc2 = acc0, acc3 = acc0;
  const float cs = 0.17677669529663687f;   // 1/sqrt(32)
#pragma unroll
  for (int ks = 0; ks < 9; ks++) {
    float hs = (ks < 8) ? hip[ks] : 1.f;
    AF a = mkfrag(hs, sf);
    int c2 = (ks*4 + q)*64;
    AF b0, b1f, b2, b3;
    b0.q  = *(const uint4*)&ipT[(c2 +  0 + m)*8];
    b1f.q = *(const uint4*)&ipT[(c2 + 16 + m)*8];
    b2.q  = *(const uint4*)&ipT[(c2 + 32 + m)*8];
    b3.q  = *(const uint4*)&ipT[(c2 + 48 + m)*8];
    acc0 = __builtin_amdgcn_mfma_f32_16x16x32_f16(a.v, b0.v,  acc0, 0, 0, 0);
    acc1 = __builtin_amdgcn_mfma_f32_16x16x32_f16(a.v, b1f.v, acc1, 0, 0, 0);
    acc2 = __builtin_amdgcn_mfma_f32_16x16x32_f16(a.v, b2.v,  acc2, 0, 0, 0);
    acc3 = __builtin_amdgcn_mfma_f32_16x16x32_f16(a.v, b3.v,  acc3, 0, 0, 0);
  }
#pragma unroll
  for (int r = 0; r < 4; r++) {
    int et = tile*16 + q*4 + r;
    u16* mp = msg + (size_t)et*128;
    mp[m]      = f2bf(cs*acc0[r]);
    mp[16 + m] = f2bf(cs*acc1[r]);
    float s0v = __shfl(sh0, q*4 + r, 64);
    float s1v = __shfl(sh1, q*4 + r, 64);
    float s2v = __shfl(sh2, q*4 + r, 64);
    float m0 = cs*acc2[r], m1 = cs*acc3[r];
    mp[32 +      m] = f2bf(m0*s0v);
    mp[64 +      m] = f2bf(m0*s1v);
    mp[96 +      m] = f2bf(m0*s2v);
    mp[32 + 16 + m] = f2bf(m1*s0v);
    mp[64 + 16 + m] = f2bf(m1*s1v);
    mp[96 + 16 + m] = f2bf(m1*s2v);
  }
}

// ---- conv2: one wave per tile, ZERO LDS/barriers; B-fragments from lyT (L2) ----
__global__ __launch_bounds__(256) void k_conv2(
    const float* __restrict__ hE, const float* __restrict__ sh,
    const float* __restrict__ s1, const float* __restrict__ v1soa,
    const int* __restrict__ eidx, const u16* __restrict__ lyT,
    u16* __restrict__ msgA, u16* __restrict__ msgB) {
  int wid = threadIdx.x >> 6, lane = threadIdx.x & 63;
  const bool scalarHalf = blockIdx.x < 625;
  int blk = scalarHalf ? blockIdx.x : blockIdx.x - 625;
  int tile = blk*4 + wid;                  // grid = 1250 blocks
  int m = lane & 15, q = lane >> 4;
  const u16* Bg = lyT + (scalarHalf ? 0 : 18432);
  const float c = 0.125f;  // 1/sqrt(64)
  int e = tile*16 + m;
  int srcn = eidx[e];
  float4 hA = *(const float4*)&hE[e*8];
  float4 hB = *(const float4*)&hE[e*8 + 4];
  float hf[8] = {hA.x,hA.y,hA.z,hA.w,hB.x,hB.y,hB.z,hB.w};

  if (scalarHalf) {
    float4 sA = *(const float4*)&s1[srcn*32 + q*8];
    float4 sB = *(const float4*)&s1[srcn*32 + q*8 + 4];
    float sf[8] = {sA.x,sA.y,sA.z,sA.w,sB.x,sB.y,sB.z,sB.w};
    f32x4 acc0 = {0.f,0.f,0.f,0.f}, acc1 = acc0, acc2 = acc0, acc3 = acc0;
#pragma unroll
    for (int ks = 0; ks < 9; ks++) {
      float hs = (ks < 8) ? hf[ks] : 1.f;
      AF a = mkfrag(hs, sf);
      int c2 = (ks*4 + q)*64;
      AF b0, b1f, b2, b3;
      b0.q  = *(const uint4*)&Bg[(c2 +  0 + m)*8];
      b1f.q = *(const uint4*)&Bg[(c2 + 16 + m)*8];
      b2.q  = *(const uint4*)&Bg[(c2 + 32 + m)*8];
      b3.q  = *(const uint4*)&Bg[(c2 + 48 + m)*8];
      acc0 = __builtin_amdgcn_mfma_f32_16x16x32_f16(a.v, b0.v,  acc0, 0, 0, 0);
      acc1 = __builtin_amdgcn_mfma_f32_16x16x32_f16(a.v, b1f.v, acc1, 0, 0, 0);
      acc2 = __builtin_amdgcn_mfma_f32_16x16x32_f16(a.v, b2.v,  acc2, 0, 0, 0);
      acc3 = __builtin_amdgcn_mfma_f32_16x16x32_f16(a.v, b3.v,  acc3, 0, 0, 0);
    }
#pragma unroll
    for (int r = 0; r < 4; r++) {
      int et = tile*16 + q*4 + r;
      u16* mp = msgA + (size_t)et*128;
      mp[m]      = f2bf(c*acc0[r]);
      mp[16 + m] = f2bf(c*acc1[r]);
      float s0v = sh[et*3+0], s1v = sh[et*3+1], s2v = sh[et*3+2];
      float m0 = c*acc2[r], m1 = c*acc3[r];
      mp[32 +      m] = f2bf(m0*s0v);
      mp[64 +      m] = f2bf(m0*s1v);
      mp[96 +      m] = f2bf(m0*s2v);
      mp[32 + 16 + m] = f2bf(m1*s0v);
      mp[64 + 16 + m] = f2bf(m1*s1v);
      mp[96 + 16 + m] = f2bf(m1*s2v);
    }
  } else {
    const float is3 = 0.5773502691896258f;
    float vf[3][8];
#pragma unroll
    for (int i = 0; i < 3; i++) {
      float4 aa = *(const float4*)&v1soa[i*160000 + srcn*32 + q*8];
      float4 bb = *(const float4*)&v1soa[i*160000 + srcn*32 + q*8 + 4];
      vf[i][0]=aa.x; vf[i][1]=aa.y; vf[i][2]=aa.z; vf[i][3]=aa.w;
      vf[i][4]=bb.x; vf[i][5]=bb.y; vf[i][6]=bb.z; vf[i][7]=bb.w;
    }
    float es0 = sh[e*3+0], es1 = sh[e*3+1], es2 = sh[e*3+2];
    float df[8];
#pragma unroll
    for (int j = 0; j < 8; j++)
      df[j] = (vf[0][j]*es0 + vf[1][j]*es1 + vf[2][j]*es2) * is3;
    f32x4 z = {0.f,0.f,0.f,0.f};
    f32x4 aV00 = z, aV01 = z, aV10 = z, aV11 = z, aV20 = z, aV21 = z, aD0 = z, aD1 = z;
#pragma unroll
    for (int ks = 0; ks < 9; ks++) {
      float hs = (ks < 8) ? hf[ks] : 1.f;
      int c2 = (ks*4 + q)*64;
      AF b0, b1f, b2, b3;
      b0.q  = *(const uint4*)&Bg[(c2 +  0 + m)*8];
      b1f.q = *(const uint4*)&Bg[(c2 + 16 + m)*8];
      b2.q  = *(const uint4*)&Bg[(c2 + 32 + m)*8];
      b3.q  = *(const uint4*)&Bg[(c2 + 48 + m)*8];
      AF a0 = mkfrag(hs, vf[0]);
      AF a1 = mkfrag(hs, vf[1]);
      AF a2 = mkfrag(hs, vf[2]);
      AF ad = mkfrag(hs, df);
      aV00 = __builtin_amdgcn_mfma_f32_16x16x32_f16(a0.v, b0.v,  aV00, 0, 0, 0);
      aV01 = __builtin_amdgcn_mfma_f32_16x16x32_f16(a0.v, b1f.v, aV01, 0, 0, 0);
      aV10 = __builtin_amdgcn_mfma_f32_16x16x32_f16(a1.v, b0.v,  aV10, 0, 0, 0);
      aV11 = __builtin_amdgcn_mfma_f32_16x16x32_f16(a1.v, b1f.v, aV11, 0, 0, 0);
      aV20 = __builtin_amdgcn_mfma_f32_16x16x32_f16(a2.v, b0.v,  aV20, 0, 0, 0);
      aV21 = __builtin_amdgcn_mfma_f32_16x16x32_f16(a2.v, b1f.v, aV21, 0, 0, 0);
      aD0  = __builtin_amdgcn_mfma_f32_16x16x32_f16(ad.v, b2.v,  aD0,  0, 0, 0);
      aD1  = __builtin_amdgcn_mfma_f32_16x16x32_f16(ad.v, b3.v,  aD1,  0, 0, 0);
    }
#pragma unroll
    for (int r = 0; r < 4; r++) {
      int et = tile*16 + q*4 + r;
      u16* mp = msgB + (size_t)et*128;
      mp[m]      = f2bf(c*aD0[r]);
      mp[16 + m] = f2bf(c*aD1[r]);
      mp[32 +      m] = f2bf(c*aV00[r]);
      mp[32 + 16 + m] = f2bf(c*aV01[r]);
      mp[64 +      m] = f2bf(c*aV10[r]);
      mp[64 + 16 + m] = f2bf(c*aV11[r]);
      mp[96 +      m] = f2bf(c*aV20[r]);
      mp[96 + 16 + m] = f2bf(c*aV21[r]);
    }
  }
}

// ---- gather + mean (conv1); perm in LDS; 4-way unrolled loads ----
__global__ __launch_bounds__(256) void k_gather1(
    const u16* __restrict__ msg, const int* __restrict__ perm,
    const int* __restrict__ cur, float* __restrict__ s1,
    float* __restrict__ v1soa) {
  __shared__ int pe[2][64];
  int ln = threadIdx.x >> 7, c = threadIdx.x & 127;
  int n = blockIdx.x*2 + ln;
  int deg = min(cur[n], 64);
  if (c < 64) pe[ln][c] = perm[n*64 + c];
  __syncthreads();
  float acc = 0.f;
  int j = 0;
  for (; j + 4 <= deg; j += 4) {
    int e0 = pe[ln][j], e1 = pe[ln][j+1], e2 = pe[ln][j+2], e3 = pe[ln][j+3];
    float x0 = __uint_as_float(((u32)msg[(size_t)e0*128 + c]) << 16);
    float x1 = __uint_as_float(((u32)msg[(size_t)e1*128 + c]) << 16);
    float x2 = __uint_as_float(((u32)msg[(size_t)e2*128 + c]) << 16);
    float x3 = __uint_as_float(((u32)msg[(size_t)e3*128 + c]) << 16);
    acc += (x0 + x1) + (x2 + x3);
  }
  for (; j < deg; j++)
    acc += __uint_as_float(((u32)msg[(size_t)pe[ln][j]*128 + c]) << 16);
  acc /= (float)max(deg, 1);
  if (c < 32) s1[n*32 + c] = acc;
  else { int i = (c-32) >> 5, w = (c-32) & 31; v1soa[i*160000 + n*32 + w] = acc; }
}

// ---- gather + mean (conv2) + self-interaction + node MLP; unrolled loads ----
__global__ __launch_bounds__(256) void k_gather2(
    const u16* __restrict__ msgA, const u16* __restrict__ msgB,
    const int* __restrict__ perm, const int* __restrict__ cur,
    const float* __restrict__ s1, const float* __restrict__ v1soa,
    const float* __restrict__ Ws, const float* __restrict__ Wv,
    const float* __restrict__ noW1, const float* __restrict__ noW2,
    float* __restrict__ s2, float* __restrict__ v2, float* __restrict__ outN) {
  __shared__ int pe[2][64];
  __shared__ float sb[2][32];
  __shared__ float hb[2][13];
  int ln = threadIdx.x >> 7, c = threadIdx.x & 127;
  int n = blockIdx.x*2 + ln;
  int deg = min(cur[n], 64);
  if (c < 64) pe[ln][c] = perm[n*64 + c];
  __syncthreads();
  float acc = 0.f;
  int j = 0;
  for (; j + 4 <= deg; j += 4) {
    int e0 = pe[ln][j], e1 = pe[ln][j+1], e2 = pe[ln][j+2], e3 = pe[ln][j+3];
    float x0 = __uint_as_float(((u32)msgA[(size_t)e0*128 + c]) << 16)
             + __uint_as_float(((u32)msgB[(size_t)e0*128 + c]) << 16);
    float x1 = __uint_as_float(((u32)msgA[(size_t)e1*128 + c]) << 16)
             + __uint_as_float(((u32)msgB[(size_t)e1*128 + c]) << 16);
    float x2 = __uint_as_float(((u32)msgA[(size_t)e2*128 + c]) << 16)
             + __uint_as_float(((u32)msgB[(size_t)e2*128 + c]) << 16);
    float x3 = __uint_as_float(((u32)msgA[(size_t)e3*128 + c]) << 16)
             + __uint_as_float(((u32)msgB[(size_t)e3*128 + c]) << 16);
    acc += (x0 + x1) + (x2 + x3);
  }
  for (; j < deg; j++) {
    int e = pe[ln][j];
    acc += __uint_as_float(((u32)msgA[(size_t)e*128 + c]) << 16)
         + __uint_as_float(((u32)msgB[(size_t)e*128 + c]) << 16);
  }
  acc /= (float)max(deg, 1);
  const float lc = 0.17677669529663687f;  // 1/sqrt(32)
  if (c < 32) {
    float ss = 0.f;
#pragma unroll 8
    for (int u = 0; u < 32; u++) ss += s1[n*32 + u] * Ws[u*32 + c];
    float val = acc + lc*ss;
    s2[n*32 + c] = val;
    sb[ln][c] = val;
  } else {
    int i = (c-32) >> 5, w = (c-32) & 31;
    float sv = 0.f;
#pragma unroll 8
    for (int u = 0; u < 32; u++) sv += v1soa[i*160000 + n*32 + u] * Wv[u*32 + w];
    v2[n*96 + w*3 + i] = acc + lc*sv;
  }
  __syncthreads();
  const float i32 = 0.17677669529663687f;
  if (c < 13) {
    float a = 0.f;
#pragma unroll 8
    for (int u = 0; u < 32; u++) a += sb[ln][u] * noW1[u*13 + c];
    hb[ln][c] = siluf(a * i32);
  }
  __syncthreads();
  const float i13 = 0.2773500981126146f;  // 1/sqrt(13)
  if (c < 13) {
    float a = 0.f;
#pragma unroll
    for (int j2 = 0; j2 < 13; j2++) a += hb[ln][j2] * noW2[j2*13 + c];
    outN[n*13 + c] = a * i13;
  }
}

// ---- edge output TP -> 5x0e; lanes = u, 2 edges per pass, path-major inner loop ----
__global__ __launch_bounds__(256) void k_e3(
    const float* __restrict__ hE, const float* __restrict__ sh,
    const float* __restrict__ s2, const float* __restrict__ v2,
    const int* __restrict__ eidx,
    const float* __restrict__ W1, const float* __restrict__ b1,
    float* __restrict__ out) {
  __shared__ uint4 WQ[640];   // [(p*5+w)*32 + u] : 8 bf16 k-values
  __shared__ float BQ[640];
  for (int t = threadIdx.x; t < 640; t += 256) {
    int u = t & 31, pw = t >> 5, p2 = pw / 5, w = pw - p2*5;
    int col = p2*160 + u*5 + w;
    const float* s = W1 + col;
    uint4 q;
    q.x = packbf2(s[0],      s[640]);
    q.y = packbf2(s[1280],   s[1920]);
    q.z = packbf2(s[2560],   s[3200]);
    q.w = packbf2(s[3840],   s[4480]);
    WQ[t] = q;
    BQ[t] = b1[col];
  }
  __syncthreads();
  const int g = threadIdx.x >> 5, tw = threadIdx.x & 31;
  const float c = 0.08838834764831845f;   // 1/sqrt(128)
  const float is3 = 0.5773502691896258f;
  for (int p = blockIdx.x*8 + g; p*2 < NE; p += gridDim.x*8) {
    int e0 = p*2, e1 = e0 + 1;
    float h0[8], h1[8];
    {
      float4 qa = *(const float4*)&hE[e0*8];
      float4 qb = *(const float4*)&hE[e0*8+4];
      h0[0]=qa.x; h0[1]=qa.y; h0[2]=qa.z; h0[3]=qa.w;
      h0[4]=qb.x; h0[5]=qb.y; h0[6]=qb.z; h0[7]=qb.w;
      float4 qc = *(const float4*)&hE[e1*8];
      float4 qd = *(const float4*)&hE[e1*8+4];
      h1[0]=qc.x; h1[1]=qc.y; h1[2]=qc.z; h1[3]=qc.w;
      h1[4]=qd.x; h1[5]=qd.y; h1[6]=qd.z; h1[7]=qd.w;
    }
    int sA = eidx[e0], dA = eidx[NE+e0];
    int sB = eidx[e1], dB = eidx[NE+e1];
    float sa0 = sh[e0*3+0], sa1 = sh[e0*3+1], sa2 = sh[e0*3+2];
    float sb0 = sh[e1*3+0], sb1 = sh[e1*3+1], sb2 = sh[e1*3+2];
    float c00 = s2[sA*32 + tw];
    float c01 = (v2[sA*96+tw*3+0]*sa0 + v2[sA*96+tw*3+1]*sa1 + v2[sA*96+tw*3+2]*sa2) * is3;
    float c02 = s2[dA*32 + tw];
    float c03 = (v2[dA*96+tw*3+0]*sa0 + v2[dA*96+tw*3+1]*sa1 + v2[dA*96+tw*3+2]*sa2) * is3;
    float c10 = s2[sB*32 + tw];
    float c11 = (v2[sB*96+tw*3+0]*sb0 + v2[sB*96+tw*3+1]*sb1 + v2[sB*96+tw*3+2]*sb2) * is3;
    float c12 = s2[dB*32 + tw];
    float c13 = (v2[dB*96+tw*3+0]*sb0 + v2[dB*96+tw*3+1]*sb1 + v2[dB*96+tw*3+2]*sb2) * is3;
    float part0[5] = {0,0,0,0,0};
    float part1[5] = {0,0,0,0,0};
#pragma unroll
    for (int pp = 0; pp < 4; pp++) {
      float cp0 = (pp==0) ? c00 : (pp==1) ? c01 : (pp==2) ? c02 : c03;
      float cp1 = (pp==0) ? c10 : (pp==1) ? c11 : (pp==2) ? c12 : c13;
#pragma unroll
      for (int w = 0; w < 5; w++) {
        int idx = (pp*5 + w)*32 + tw;
        float f[8];
        unpack8(WQ[idx], f);
        float bv = BQ[idx];
        part0[w] = fmaf(cp0, dot8f(h0, f, bv), part0[w]);
        part1[w] = fmaf(cp1, dot8f(h1, f, bv), part1[w]);
      }
    }
#pragma unroll
    for (int off = 16; off > 0; off >>= 1)
#pragma unroll
      for (int w = 0; w < 5; w++) {
        part0[w] += __shfl_xor(part0[w], off, 32);
        part1[w] += __shfl_xor(part1[w], off, 32);
      }
    float outv = 0.f;
#pragma unroll
    for (int w = 0; w < 5; w++) {
      if (tw == w)     outv = part0[w];
      if (tw == 5 + w) outv = part1[w];
    }
    if (tw < 10) out[e0*5 + tw] = c * outv;
  }
}

extern "C" void kernel_launch(void* const* d_in, const int* in_sizes, int n_in,
                              void* d_out, int out_size, void* d_ws, size_t ws_size,
                              hipStream_t stream) {
  (void)in_sizes; (void)n_in; (void)out_size; (void)ws_size;
  const float* coords = (const float*)d_in[0];
  const int*   atype  = (const int*)d_in[1];
  const int*   eidx   = (const int*)d_in[2];
  const float* emb    = (const float*)d_in[3];
  const float* ipW0 = (const float*)d_in[4];
  const float* ipb0 = (const float*)d_in[5];
  const float* ipW1 = (const float*)d_in[6];
  const float* ipb1 = (const float*)d_in[7];
  const float* lyW0 = (const float*)d_in[8];
  const float* lyb0 = (const float*)d_in[9];
  const float* lyW1 = (const float*)d_in[10];
  const float* lyb1 = (const float*)d_in[11];
  const float* lyWs = (const float*)d_in[12];
  const float* lyWv = (const float*)d_in[13];
  const float* etW0 = (const float*)d_in[14];
  const float* etb0 = (const float*)d_in[15];
  const float* etW1 = (const float*)d_in[16];
  const float* etb1 = (const float*)d_in[17];
  const float* noW1 = (const float*)d_in[18];
  const float* noW2 = (const float*)d_in[19];

  float* ws = (float*)d_ws;
  float* sh    = ws;                  // E*3
  float* h_ly  = ws + 440000;         // E*8
  float* h_et  = ws + 760000;         // E*8
  float* s1    = ws + 1240000;        // N*32
  float* v1soa = ws + 1400000;        // 3 x 160000 (SoA)
  float* s2    = ws + 1880000;        // N*32
  float* v2    = ws + 2040000;        // N*96 (AoS) -> ends 2520000
  int*   cur   = (int*)(ws + 2520000);   // N ints (poison sentinel, CAS-zeroed)
  int*   perm  = (int*)(ws + 2525000);   // N*64 ints
  u16*   msgA  = (u16*)(ws + 2845000);   // E*128 bf16
  u16*   msgB  = (u16*)(ws + 5405000);   // E*128 bf16 -> ends 7965000
  u16*   lyT   = (u16*)(ws + 7965000);   // 2*18432 f16 -> ends 7983432
  u16*   ipT   = (u16*)(ws + 7983432);   // 18432 f16

  float* outE = (float*)d_out;            // E*5
  float* outN = (float*)d_out + NE*5;     // N*13

  k_prep<<<8, 256, 0, stream>>>(ipW1, ipb1, ipT);
  k_conv1<<<641, 256, 0, stream>>>(coords, eidx, emb, atype,
                                   ipW0, ipb0, lyW0, lyb0, etW0, etb0,
                                   lyW1, lyb1, ipT,
                                   sh, h_ly, h_et, cur, perm, msgA, lyT);
  k_gather1<<<NN/2, 256, 0, stream>>>(msgA, perm, cur, s1, v1soa);
  k_conv2<<<1250, 256, 0, stream>>>(h_ly, sh, s1, v1soa, eidx, lyT, msgA, msgB);
  k_gather2<<<NN/2, 256, 0, stream>>>(msgA, msgB, perm, cur, s1, v1soa,
                                      lyWs, lyWv, noW1, noW2, s2, v2, outN);
  k_e3<<<1024, 256, 0, stream>>>(h_et, sh, s2, v2, eidx, etW1, etb1, outE);
}